// Round 16
// baseline (608.607 us; speedup 1.0000x reference)
//
#include <hip/hip_runtime.h>
#include <math.h>

#define TT 256
#define FF 64
#define HH 20
#define G4 80   // 4*H
#define PBLK 320
#define RBLK 704   // 5 waves L1 | 5 waves L2 | 1 wave PROJ-MFMA
#define BLOB_BYTES 19456   // 15*80 float4
#define WTHI_OFF 19456     // 80*64 ushort = 10240
#define WTLO_OFF 29696
#define WS_NEED  39936

typedef __attribute__((ext_vector_type(8))) short short8x;
typedef __attribute__((ext_vector_type(4))) float f32x4;

__device__ __forceinline__ float sigmoidf_(float z) {
    return __builtin_amdgcn_rcpf(1.0f + __expf(-z));
}
__device__ __forceinline__ float qpx1(float v) {
    return __int_as_float(__builtin_amdgcn_mov_dpp(__float_as_int(v), 0xB1, 0xF, 0xF, true));
}
__device__ __forceinline__ float qpx2(float v) {
    return __int_as_float(__builtin_amdgcn_mov_dpp(__float_as_int(v), 0x4E, 0xF, 0xF, true));
}
__device__ __forceinline__ float qpx3(float v) {
    return __int_as_float(__builtin_amdgcn_mov_dpp(__float_as_int(v), 0x1B, 0xF, 0xF, true));
}
__device__ __forceinline__ unsigned short bft(float f) {   // truncate to bf16
    return (unsigned short)(__float_as_uint(f) >> 16);
}

// ===== K0: (a) rec blob (R10-proven); (b) W1 -> p-ORDERED transposed bf16 hi/lo
// wthi[p][f] = hi(W1[f][col(p)]), col(p) = (p&3)*20 + (p>>2) — so the fused
// kernel's ring can be stored in j-order and rec reads ring[t][elem][j] directly.
__global__ void wprep(const float* __restrict__ U1, const float* __restrict__ W2,
                      const float* __restrict__ U2, const float* __restrict__ W1,
                      float4* __restrict__ blob,
                      unsigned short* __restrict__ wthi, unsigned short* __restrict__ wtlo) {
    int i = threadIdx.x + blockIdx.x * blockDim.x;
    if (i < 15 * G4) {
        int q = i / G4, j = i - q * G4;
        int m = q / 5, kq = q - m * 5;
        int col = (j & 3) * HH + (j >> 2);
        const float* M = (m == 0) ? U1 : (m == 1) ? W2 : U2;
        float4 v;
        v.x = M[(kq * 4 + 0) * G4 + col];
        v.y = M[(kq * 4 + 1) * G4 + col];
        v.z = M[(kq * 4 + 2) * G4 + col];
        v.w = M[(kq * 4 + 3) * G4 + col];
        blob[i] = v;
    } else if (i < 15 * G4 + FF * G4) {
        int idx = i - 15 * G4;
        int p = idx / FF, f = idx - p * FF;
        int col = (p & 3) * HH + (p >> 2);
        float w = W1[f * G4 + col];
        unsigned short h = bft(w);
        float fh = __uint_as_float((unsigned)h << 16);
        wthi[p * FF + f] = h;
        wtlo[p * FF + f] = bft(w - fh);
    }
}

// ===== Fused kernel: L1/L2 producer-consumer rec (R13-proven) + 1 PROJ-MFMA wave
// PROJ wave: burst at iter k (k%4==0, 4<=k<=TT-8) computes xw(t=k+4..k+7) for the
// block's 4 elems via split-bf16 MFMA (M=16 rows = elem*4+tloc), writes LDS ring.
// Ring slot s=(t&7): written >=1 barrier before read (t read at iter t), rewritten
// (t+8) >=1 barrier after. Prologue fills t=0..7. No global xw traffic at all.
__global__ __launch_bounds__(RBLK, 6) void lstm2_all(
    const float* __restrict__ x, const float4* __restrict__ blob,
    const unsigned short* __restrict__ wthi, const unsigned short* __restrict__ wtlo,
    const float* __restrict__ b1, const float* __restrict__ b2,
    const float* __restrict__ Wd, const float* __restrict__ bd,
    float* __restrict__ out, int B)
{
    const int tid = threadIdx.x;
    const int b0  = blockIdx.x * 4;

    __shared__ float h1b[2][4][24];
    __shared__ float h2b[2][4][24];
    __shared__ float ring[8][4][84];          // 84-pad: elem stride 336B breaks mod-32 alias
    __shared__ unsigned short Bthi[G4][72];   // W1 hi (p-order), 72-pad
    __shared__ unsigned short Btlo[G4][72];

    // ---- stage W1 hi/lo; zero h buffers (all threads) ----
    for (int c = tid; c < G4 * FF / 8; c += RBLK) {
        int row = c >> 3, cc = (c & 7) * 8;
        *(short8x*)&Bthi[row][cc] = *(const short8x*)&wthi[row * FF + cc];
        *(short8x*)&Btlo[row][cc] = *(const short8x*)&wtlo[row * FF + cc];
    }
    for (int i = tid; i < 2 * 4 * 24; i += RBLK) ((float*)h1b)[i] = 0.f;
    for (int i = tid; i < 2 * 4 * 24; i += RBLK) ((float*)h2b)[i] = 0.f;

    const int role = (tid < 320) ? 0 : (tid < 640) ? 1 : 2;

    // ---- rec-role setup (roles 0/1), R13-identical ----
    const int rt   = (role == 1) ? tid - 320 : tid;   // role 2 unused
    const int elem = (rt / G4) & 3;
    const int j    = rt - (rt / G4) * G4;
    const int g    = j & 3;
    const int u    = j >> 2;
    const int col  = g * HH + u;

    float wA[HH], wB[HH];
    float bias = 0.f;
    if (role == 0) {
        const float4* wb4 = blob + j;
#pragma unroll
        for (int q = 0; q < 5; ++q) {
            float4 v = wb4[q * G4];
            wA[4*q+0] = v.x; wA[4*q+1] = v.y; wA[4*q+2] = v.z; wA[4*q+3] = v.w;
        }
    } else if (role == 1) {
        const float4* wb4 = blob + j;
#pragma unroll
        for (int q = 0; q < 5; ++q) {
            float4 v = wb4[(5 + q) * G4];
            wA[4*q+0] = v.x; wA[4*q+1] = v.y; wA[4*q+2] = v.z; wA[4*q+3] = v.w;
            float4 v2 = wb4[(10 + q) * G4];
            wB[4*q+0] = v2.x; wB[4*q+1] = v2.y; wB[4*q+2] = v2.z; wB[4*q+3] = v2.w;
        }
        bias = b2[col];
    }

    // ---- PROJ-role setup (role 2): lane geometry + bias ----
    const int pl  = tid - 640;           // 0..63 (valid for role 2)
    const int i0  = pl & 15;             // C col / A row-group index
    const int lg  = pl >> 4;             // k/row group
    const int ae  = i0 >> 2, at = i0 & 3;
    float biasp[5];
    if (role == 2) {
#pragma unroll
        for (int nt = 0; nt < 5; ++nt) {
            int p = nt * 16 + i0;
            biasp[nt] = b1[(p & 3) * HH + (p >> 2)];
        }
    }

    // burst: compute xw(t=tb..tb+3) for 4 elems into ring (split-bf16 MFMA, M=16)
    auto burst = [&](int tb) {
        short8x Ah[2], Al[2];
        const float* xr = x + ((size_t)(b0 + ae) * TT + (tb + at)) * FF + lg * 8;
#pragma unroll
        for (int ks = 0; ks < 2; ++ks) {
            float4 va = *(const float4*)(xr + ks * 32);
            float4 vb = *(const float4*)(xr + ks * 32 + 4);
            float v[8] = {va.x, va.y, va.z, va.w, vb.x, vb.y, vb.z, vb.w};
#pragma unroll
            for (int e = 0; e < 8; ++e) {
                unsigned short h = bft(v[e]);
                float fh = __uint_as_float((unsigned)h << 16);
                Ah[ks][e] = (short)h;
                Al[ks][e] = (short)bft(v[e] - fh);
            }
        }
#pragma unroll
        for (int nt = 0; nt < 5; ++nt) {
            f32x4 acc = (f32x4){0.f, 0.f, 0.f, 0.f};
#pragma unroll
            for (int ks = 0; ks < 2; ++ks) {
                short8x bh = *(const short8x*)&Bthi[nt * 16 + i0][ks * 32 + lg * 8];
                short8x bl = *(const short8x*)&Btlo[nt * 16 + i0][ks * 32 + lg * 8];
                acc = __builtin_amdgcn_mfma_f32_16x16x32_bf16(Ah[ks], bh, acc, 0, 0, 0);
                acc = __builtin_amdgcn_mfma_f32_16x16x32_bf16(Al[ks], bh, acc, 0, 0, 0);
                acc = __builtin_amdgcn_mfma_f32_16x16x32_bf16(Ah[ks], bl, acc, 0, 0, 0);
            }
#pragma unroll
            for (int r = 0; r < 4; ++r) {
                int row = lg * 4 + r;     // C row = M index = elem*4 + tloc
                ring[(tb + (row & 3)) & 7][row >> 2][nt * 16 + i0] = acc[r] + biasp[nt];
            }
        }
    };

    __syncthreads();                      // Bthi/Btlo staged

    if (role == 2) { burst(0); burst(4); }  // prologue: t=0..7
    float c1 = 0.f, c2 = 0.f;
    __syncthreads();

    for (int i = 0; i <= TT; ++i) {
        const int rb = (i + 1) & 1;
        const int wb = i & 1;

        if (role == 0) {
            if (i < TT) {
                float xwc = ring[i & 7][elem][j];
                float zz0 = 0.f, zz1 = 0.f, zz2 = 0.f, zz3 = 0.f;
                const float4* hv = (const float4*)h1b[rb][elem];
#pragma unroll
                for (int q = 0; q < 5; ++q) {
                    float4 hh = hv[q];
                    zz0 = fmaf(hh.x, wA[4*q+0], zz0);
                    zz1 = fmaf(hh.y, wA[4*q+1], zz1);
                    zz2 = fmaf(hh.z, wA[4*q+2], zz2);
                    zz3 = fmaf(hh.w, wA[4*q+3], zz3);
                }
                float z = xwc + ((zz0 + zz1) + (zz2 + zz3));
                float a = (g == 2) ? fmaxf(z, 0.f) : sigmoidf_(z);
                float a1 = qpx1(a), a2 = qpx2(a), a3 = qpx3(a);
                c1 = a1 * c1 + a * a2;
                float h1n = a3 * fmaxf(c1, 0.f);
                if (g == 0) h1b[wb][elem][u] = h1n;
            }
        } else if (role == 1) {
            if (i >= 1) {
                float y0 = 0.f, y1 = 0.f, y2 = 0.f, y3 = 0.f;
                const float4* h1v = (const float4*)h1b[rb][elem];
                const float4* h2v = (const float4*)h2b[rb][elem];
#pragma unroll
                for (int q = 0; q < 5; ++q) {
                    float4 ha = h1v[q];
                    float4 hb = h2v[q];
                    y0 = fmaf(ha.x, wA[4*q+0], y0);
                    y1 = fmaf(ha.y, wA[4*q+1], y1);
                    y2 = fmaf(ha.z, wA[4*q+2], y2);
                    y3 = fmaf(ha.w, wA[4*q+3], y3);
                    y0 = fmaf(hb.x, wB[4*q+0], y0);
                    y1 = fmaf(hb.y, wB[4*q+1], y1);
                    y2 = fmaf(hb.z, wB[4*q+2], y2);
                    y3 = fmaf(hb.w, wB[4*q+3], y3);
                }
                float z2v = bias + ((y0 + y1) + (y2 + y3));
                float bgt = (g == 2) ? fmaxf(z2v, 0.f) : sigmoidf_(z2v);
                float b1_ = qpx1(bgt), b2_ = qpx2(bgt), b3_ = qpx3(bgt);
                c2 = b1_ * c2 + bgt * b2_;
                float h2n = b3_ * fmaxf(c2, 0.f);
                if (g == 0) h2b[wb][elem][u] = h2n;
            }
        } else {
            // burst at k%4==0, k>=4, writes t=k+4..k+7 (slots disjoint from reads k..k+3)
            if ((i & 3) == 0 && i >= 4 && i <= TT - 8) burst(i + 4);
        }
        __syncthreads();
    }

    // dense head: final h2(255) in h2b[0]
    if (tid < 4) {
        float acc = bd[0];
#pragma unroll
        for (int k = 0; k < HH; ++k) acc += h2b[0][tid][k] * Wd[k];
        out[b0 + tid] = acc;
    }
}

// ================= Fallback (ws too small): fused single kernel =================
__global__ __launch_bounds__(PBLK, 2) void lstm2_fused_fb(
    const float* __restrict__ x,
    const float* __restrict__ W1, const float* __restrict__ U1, const float* __restrict__ b1,
    const float* __restrict__ W2, const float* __restrict__ U2, const float* __restrict__ b2,
    const float* __restrict__ Wd, const float* __restrict__ bd,
    float* __restrict__ out)
{
    const int tid  = threadIdx.x;
    const int elem = tid / G4;
    const int j    = tid - elem * G4;
    const int g    = j & 3;
    const int u    = j >> 2;
    const int col  = g * HH + u;
    const int b0   = blockIdx.x * 4;

    __shared__ float xs[2][4][FF];
    __shared__ float h1b[2][4][24];
    __shared__ float h2b[2][4][24];

    float w1[FF], u1[HH], w2[HH], u2[HH];
#pragma unroll
    for (int f = 0; f < FF; ++f) w1[f] = W1[f * G4 + col];
#pragma unroll
    for (int k = 0; k < HH; ++k) u1[k] = U1[k * G4 + col];
#pragma unroll
    for (int k = 0; k < HH; ++k) w2[k] = W2[k * G4 + col];
#pragma unroll
    for (int k = 0; k < HH; ++k) u2[k] = U2[k * G4 + col];
    const float bias1 = b1[col];
    const float bias2 = b2[col];

    for (int i = tid; i < 2 * 4 * 24; i += PBLK) ((float*)h1b)[i] = 0.f;
    for (int i = tid; i < 2 * 4 * 24; i += PBLK) ((float*)h2b)[i] = 0.f;
    if (tid < 4 * FF) {
        int e2 = tid >> 6, f2 = tid & 63;
        xs[0][e2][f2] = x[((long)(b0 + e2) * TT + 0) * FF + f2];
    }
    __syncthreads();

    float c1 = 0.f, c2 = 0.f;
    for (int t = 0; t < TT; ++t) {
        const int cur = t & 1;
        float xpre = 0.f;
        if (t + 1 < TT && tid < 4 * FF) {
            int e2 = tid >> 6, f2 = tid & 63;
            xpre = x[((long)(b0 + e2) * TT + (t + 1)) * FF + f2];
        }
        float zz0 = 0.f, zz1 = 0.f, zz2 = 0.f, zz3 = 0.f;
        const float4* xv = (const float4*)xs[cur][elem];
#pragma unroll
        for (int q = 0; q < FF / 4; ++q) {
            float4 xx = xv[q];
            zz0 = fmaf(xx.x, w1[4*q+0], zz0);
            zz1 = fmaf(xx.y, w1[4*q+1], zz1);
            zz2 = fmaf(xx.z, w1[4*q+2], zz2);
            zz3 = fmaf(xx.w, w1[4*q+3], zz3);
        }
        const float4* hv = (const float4*)h1b[cur][elem];
#pragma unroll
        for (int q = 0; q < HH / 4; ++q) {
            float4 hh = hv[q];
            zz0 = fmaf(hh.x, u1[4*q+0], zz0);
            zz1 = fmaf(hh.y, u1[4*q+1], zz1);
            zz2 = fmaf(hh.z, u1[4*q+2], zz2);
            zz3 = fmaf(hh.w, u1[4*q+3], zz3);
        }
        float z = bias1 + ((zz0 + zz1) + (zz2 + zz3));
        float a = (g == 2) ? fmaxf(z, 0.f) : sigmoidf_(z);
        float a1 = qpx1(a), a2 = qpx2(a), a3 = qpx3(a);
        c1 = a1 * c1 + a * a2;
        float h1n = a3 * fmaxf(c1, 0.f);
        if (g == 0) h1b[cur ^ 1][elem][u] = h1n;
        __syncthreads();
        if (t + 1 < TT && tid < 4 * FF) xs[cur ^ 1][tid >> 6][tid & 63] = xpre;

        float y0 = 0.f, y1 = 0.f, y2 = 0.f, y3 = 0.f;
        const float4* h1v = (const float4*)h1b[cur ^ 1][elem];
        const float4* h2v = (const float4*)h2b[cur][elem];
#pragma unroll
        for (int q = 0; q < HH / 4; ++q) {
            float4 ha = h1v[q];
            float4 hb = h2v[q];
            y0 = fmaf(ha.x, w2[4*q+0], y0);
            y1 = fmaf(ha.y, w2[4*q+1], y1);
            y2 = fmaf(ha.z, w2[4*q+2], y2);
            y3 = fmaf(ha.w, w2[4*q+3], y3);
            y0 = fmaf(hb.x, u2[4*q+0], y0);
            y1 = fmaf(hb.y, u2[4*q+1], y1);
            y2 = fmaf(hb.z, u2[4*q+2], y2);
            y3 = fmaf(hb.w, u2[4*q+3], y3);
        }
        float z2v = bias2 + ((y0 + y1) + (y2 + y3));
        float bgt = (g == 2) ? fmaxf(z2v, 0.f) : sigmoidf_(z2v);
        float b1_ = qpx1(bgt), b2_ = qpx2(bgt), b3_ = qpx3(bgt);
        c2 = b1_ * c2 + bgt * b2_;
        float h2n = b3_ * fmaxf(c2, 0.f);
        if (g == 0) h2b[cur ^ 1][elem][u] = h2n;
        __syncthreads();
    }
    if (j == 0) {
        float acc = bd[0];
#pragma unroll
        for (int k = 0; k < HH; ++k) acc += h2b[0][elem][k] * Wd[k];
        out[b0 + elem] = acc;
    }
}

extern "C" void kernel_launch(void* const* d_in, const int* in_sizes, int n_in,
                              void* d_out, int out_size, void* d_ws, size_t ws_size,
                              hipStream_t stream) {
    const float* x  = (const float*)d_in[0];
    const float* W1 = (const float*)d_in[1];
    const float* U1 = (const float*)d_in[2];
    const float* b1 = (const float*)d_in[3];
    const float* W2 = (const float*)d_in[4];
    const float* U2 = (const float*)d_in[5];
    const float* b2 = (const float*)d_in[6];
    const float* Wd = (const float*)d_in[7];
    const float* bd = (const float*)d_in[8];
    float* out = (float*)d_out;
    const int B = in_sizes[0] / (TT * FF);   // 2048

    if (ws_size >= (size_t)WS_NEED) {
        float4* blob = (float4*)d_ws;
        unsigned short* wthi = (unsigned short*)((char*)d_ws + WTHI_OFF);
        unsigned short* wtlo = (unsigned short*)((char*)d_ws + WTLO_OFF);
        hipLaunchKernelGGL(wprep, dim3(25), dim3(256), 0, stream,
                           U1, W2, U2, W1, blob, wthi, wtlo);
        hipLaunchKernelGGL(lstm2_all, dim3(B / 4), dim3(RBLK), 0, stream,
                           x, blob, wthi, wtlo, b1, b2, Wd, bd, out, B);
    } else {
        hipLaunchKernelGGL(lstm2_fused_fb, dim3(B / 4), dim3(PBLK), 0, stream,
                           x, W1, U1, b1, W2, U2, b2, Wd, bd, out);
    }
}

// Round 17
// 214.111 us; speedup vs baseline: 2.8425x; 2.8425x over previous
//
#include <hip/hip_runtime.h>
#include <math.h>

#define TT 256
#define FF 64
#define HH 20
#define G4 80   // 4*H
#define EPB 4   // batch elems per block (rec)
#define PBLK 320
#define RBLK 640  // 5 waves L1 + 5 waves L2
#define BLOB_BYTES 19456   // 15*80 float4
#define WTHI_OFF 19456     // 80*64 ushort = 10240
#define WTLO_OFF 29696
#define XW_OFF   40960

typedef __attribute__((ext_vector_type(8))) short short8x;
typedef __attribute__((ext_vector_type(4))) float f32x4;

__device__ __forceinline__ float sigmoidf_(float z) {
    return __builtin_amdgcn_rcpf(1.0f + __expf(-z));
}
__device__ __forceinline__ float qpx1(float v) {
    return __int_as_float(__builtin_amdgcn_mov_dpp(__float_as_int(v), 0xB1, 0xF, 0xF, true));
}
__device__ __forceinline__ float qpx2(float v) {
    return __int_as_float(__builtin_amdgcn_mov_dpp(__float_as_int(v), 0x4E, 0xF, 0xF, true));
}
__device__ __forceinline__ float qpx3(float v) {
    return __int_as_float(__builtin_amdgcn_mov_dpp(__float_as_int(v), 0x1B, 0xF, 0xF, true));
}
__device__ __forceinline__ unsigned short bft(float f) {   // truncate to bf16
    return (unsigned short)(__float_as_uint(f) >> 16);
}

// ===== K0: (a) rec blob (R10-proven); (b) W1 -> transposed bf16 hi/lo =====
__global__ void wprep(const float* __restrict__ U1, const float* __restrict__ W2,
                      const float* __restrict__ U2, const float* __restrict__ W1,
                      float4* __restrict__ blob,
                      unsigned short* __restrict__ wthi, unsigned short* __restrict__ wtlo) {
    int i = threadIdx.x + blockIdx.x * blockDim.x;
    if (i < 15 * G4) {
        int q = i / G4, j = i - q * G4;
        int m = q / 5, kq = q - m * 5;
        int col = (j & 3) * HH + (j >> 2);
        const float* M = (m == 0) ? U1 : (m == 1) ? W2 : U2;
        float4 v;
        v.x = M[(kq * 4 + 0) * G4 + col];
        v.y = M[(kq * 4 + 1) * G4 + col];
        v.z = M[(kq * 4 + 2) * G4 + col];
        v.w = M[(kq * 4 + 3) * G4 + col];
        blob[i] = v;
    } else if (i < 15 * G4 + FF * G4) {
        int idx = i - 15 * G4;
        int col = idx / FF, f = idx - col * FF;    // wt[col][f]
        float w = W1[f * G4 + col];
        unsigned short h = bft(w);
        float fh = __uint_as_float((unsigned)h << 16);
        wthi[col * FF + f] = h;
        wtlo[col * FF + f] = bft(w - fh);
    }
}

// ===== K1: split-bf16 MFMA proj (R13-proven, ≈50 µs ≈ HBM floor) =====
__global__ __launch_bounds__(256, 4) void proj_mfma(
    const float* __restrict__ x,
    const unsigned short* __restrict__ wthi, const unsigned short* __restrict__ wtlo,
    const float* __restrict__ b1, float* __restrict__ xw, int B)
{
    __shared__ unsigned short Bthi[G4][72];
    __shared__ unsigned short Btlo[G4][72];
    const int tid = threadIdx.x;
    const int l   = tid & 63;
    const int w   = tid >> 6;
    const int b   = blockIdx.x >> 1;
    const int t0  = (blockIdx.x & 1) * 128;
    const int lane16 = l & 15;
    const int lgrp   = l >> 4;

    for (int c = tid; c < G4 * FF / 8; c += 256) {
        int row = c >> 3, cc = (c & 7) * 8;
        *(short8x*)&Bthi[row][cc] = *(const short8x*)&wthi[row * FF + cc];
        *(short8x*)&Btlo[row][cc] = *(const short8x*)&wtlo[row * FF + cc];
    }
    __syncthreads();

    float bias[5];
#pragma unroll
    for (int nt = 0; nt < 5; ++nt) bias[nt] = b1[nt * 16 + lane16];

    f32x4 acc[2][5];
#pragma unroll
    for (int mt = 0; mt < 2; ++mt)
#pragma unroll
        for (int nt = 0; nt < 5; ++nt) acc[mt][nt] = (f32x4){0.f, 0.f, 0.f, 0.f};

#pragma unroll
    for (int mt = 0; mt < 2; ++mt) {
        short8x Ah[2], Al[2];
        const int trow = t0 + w * 32 + mt * 16 + lane16;
        const float* xr = x + ((size_t)b * TT + trow) * FF + lgrp * 8;
#pragma unroll
        for (int ks = 0; ks < 2; ++ks) {
            float4 va = *(const float4*)(xr + ks * 32);
            float4 vb = *(const float4*)(xr + ks * 32 + 4);
            float v[8] = {va.x, va.y, va.z, va.w, vb.x, vb.y, vb.z, vb.w};
#pragma unroll
            for (int e = 0; e < 8; ++e) {
                unsigned short h = bft(v[e]);
                float fh = __uint_as_float((unsigned)h << 16);
                Ah[ks][e] = (short)h;
                Al[ks][e] = (short)bft(v[e] - fh);
            }
        }
#pragma unroll
        for (int nt = 0; nt < 5; ++nt) {
#pragma unroll
            for (int ks = 0; ks < 2; ++ks) {
                short8x bh = *(const short8x*)&Bthi[nt * 16 + lane16][ks * 32 + lgrp * 8];
                short8x bl = *(const short8x*)&Btlo[nt * 16 + lane16][ks * 32 + lgrp * 8];
                acc[mt][nt] = __builtin_amdgcn_mfma_f32_16x16x32_bf16(Ah[ks], bh, acc[mt][nt], 0, 0, 0);
                acc[mt][nt] = __builtin_amdgcn_mfma_f32_16x16x32_bf16(Al[ks], bh, acc[mt][nt], 0, 0, 0);
                acc[mt][nt] = __builtin_amdgcn_mfma_f32_16x16x32_bf16(Ah[ks], bl, acc[mt][nt], 0, 0, 0);
            }
        }
    }

#pragma unroll
    for (int mt = 0; mt < 2; ++mt) {
        const int trb = t0 + w * 32 + mt * 16 + lgrp * 4;
#pragma unroll
        for (int nt = 0; nt < 5; ++nt) {
            const int col = nt * 16 + lane16;
#pragma unroll
            for (int r = 0; r < 4; ++r) {
                xw[((size_t)(trb + r) * B + b) * G4 + col] = acc[mt][nt][r] + bias[nt];
            }
        }
    }
}

// ============ K2: producer-consumer recurrence (R13-proven, 161 µs) ============
__global__ __launch_bounds__(RBLK, 2) void lstm2_pc(
    const float* __restrict__ xw, const float4* __restrict__ blob,
    const float* __restrict__ b2,
    const float* __restrict__ Wd, const float* __restrict__ bd,
    float* __restrict__ out, int B)
{
    const int tid  = threadIdx.x;
    const bool isL1 = tid < 320;
    const int rt   = isL1 ? tid : tid - 320;
    const int elem = rt / G4;          // 0..3
    const int j    = rt - elem * G4;   // 0..79
    const int g    = j & 3;            // gate: 0=i 1=f 2=c 3=o
    const int u    = j >> 2;           // unit 0..19
    const int col  = g * HH + u;
    const int b0   = blockIdx.x * EPB;

    __shared__ float h1b[2][EPB][24];
    __shared__ float h2b[2][EPB][24];

    const float4* wb4 = blob + j;
    float wA[HH], wB[HH];
    if (isL1) {
#pragma unroll
        for (int q = 0; q < 5; ++q) {
            float4 v = wb4[q * G4];
            wA[4*q+0] = v.x; wA[4*q+1] = v.y; wA[4*q+2] = v.z; wA[4*q+3] = v.w;
        }
    } else {
#pragma unroll
        for (int q = 0; q < 5; ++q) {
            float4 v = wb4[(5 + q) * G4];
            wA[4*q+0] = v.x; wA[4*q+1] = v.y; wA[4*q+2] = v.z; wA[4*q+3] = v.w;
            float4 v2 = wb4[(10 + q) * G4];
            wB[4*q+0] = v2.x; wB[4*q+1] = v2.y; wB[4*q+2] = v2.z; wB[4*q+3] = v2.w;
        }
    }
    const float bias = isL1 ? 0.f : b2[col];

    for (int i = tid; i < 2 * EPB * 24; i += RBLK) ((float*)h1b)[i] = 0.f;
    for (int i = tid; i < 2 * EPB * 24; i += RBLK) ((float*)h2b)[i] = 0.f;

    const size_t tstride = (size_t)B * G4;
    const float* xwp = xw + (size_t)(b0 + elem) * G4 + col;
    float xwc = isL1 ? xwp[0] : 0.f;
    xwp += tstride;
    float c1 = 0.f, c2 = 0.f;
    __syncthreads();

    for (int i = 0; i <= TT; ++i) {
        const int rb = (i + 1) & 1;    // read buffers
        const int wb = i & 1;          // write buffers

        if (isL1 && i < TT) {
            float xwn = 0.f;
            if (i + 1 < TT) xwn = *xwp;
            xwp += tstride;

            float zz0 = 0.f, zz1 = 0.f, zz2 = 0.f, zz3 = 0.f;
            const float4* hv = (const float4*)h1b[rb][elem];
#pragma unroll
            for (int q = 0; q < HH / 4; ++q) {
                float4 hh = hv[q];
                zz0 = fmaf(hh.x, wA[4*q+0], zz0);
                zz1 = fmaf(hh.y, wA[4*q+1], zz1);
                zz2 = fmaf(hh.z, wA[4*q+2], zz2);
                zz3 = fmaf(hh.w, wA[4*q+3], zz3);
            }
            float z = xwc + ((zz0 + zz1) + (zz2 + zz3));

            float a = (g == 2) ? fmaxf(z, 0.f) : sigmoidf_(z);
            float a1 = qpx1(a), a2 = qpx2(a), a3 = qpx3(a);
            c1 = a1 * c1 + a * a2;
            float h1n = a3 * fmaxf(c1, 0.f);
            if (g == 0) h1b[wb][elem][u] = h1n;
            xwc = xwn;
        }
        if (!isL1 && i >= 1) {
            float y0 = 0.f, y1 = 0.f, y2 = 0.f, y3 = 0.f;
            const float4* h1v = (const float4*)h1b[rb][elem];
            const float4* h2v = (const float4*)h2b[rb][elem];
#pragma unroll
            for (int q = 0; q < HH / 4; ++q) {
                float4 ha = h1v[q];
                float4 hb = h2v[q];
                y0 = fmaf(ha.x, wA[4*q+0], y0);
                y1 = fmaf(ha.y, wA[4*q+1], y1);
                y2 = fmaf(ha.z, wA[4*q+2], y2);
                y3 = fmaf(ha.w, wA[4*q+3], y3);
                y0 = fmaf(hb.x, wB[4*q+0], y0);
                y1 = fmaf(hb.y, wB[4*q+1], y1);
                y2 = fmaf(hb.z, wB[4*q+2], y2);
                y3 = fmaf(hb.w, wB[4*q+3], y3);
            }
            float z2v = bias + ((y0 + y1) + (y2 + y3));

            float bgt = (g == 2) ? fmaxf(z2v, 0.f) : sigmoidf_(z2v);
            float b1_ = qpx1(bgt), b2_ = qpx2(bgt), b3_ = qpx3(bgt);
            c2 = b1_ * c2 + bgt * b2_;
            float h2n = b3_ * fmaxf(c2, 0.f);
            if (g == 0) h2b[wb][elem][u] = h2n;
        }
        __syncthreads();
    }

    if (tid < EPB) {
        float acc = bd[0];
#pragma unroll
        for (int k = 0; k < HH; ++k) acc += h2b[0][tid][k] * Wd[k];
        out[b0 + tid] = acc;
    }
}

// ================= Fallback (ws too small): fused single kernel =================
__global__ __launch_bounds__(PBLK, 2) void lstm2_fused_fb(
    const float* __restrict__ x,
    const float* __restrict__ W1, const float* __restrict__ U1, const float* __restrict__ b1,
    const float* __restrict__ W2, const float* __restrict__ U2, const float* __restrict__ b2,
    const float* __restrict__ Wd, const float* __restrict__ bd,
    float* __restrict__ out)
{
    const int tid  = threadIdx.x;
    const int elem = tid / G4;
    const int j    = tid - elem * G4;
    const int g    = j & 3;
    const int u    = j >> 2;
    const int col  = g * HH + u;
    const int b0   = blockIdx.x * EPB;

    __shared__ float xs[2][EPB][FF];
    __shared__ float h1b[2][EPB][24];
    __shared__ float h2b[2][EPB][24];

    float w1[FF], u1[HH], w2[HH], u2[HH];
#pragma unroll
    for (int f = 0; f < FF; ++f) w1[f] = W1[f * G4 + col];
#pragma unroll
    for (int k = 0; k < HH; ++k) u1[k] = U1[k * G4 + col];
#pragma unroll
    for (int k = 0; k < HH; ++k) w2[k] = W2[k * G4 + col];
#pragma unroll
    for (int k = 0; k < HH; ++k) u2[k] = U2[k * G4 + col];
    const float bias1 = b1[col];
    const float bias2 = b2[col];

    for (int i = tid; i < 2 * EPB * 24; i += PBLK) ((float*)h1b)[i] = 0.f;
    for (int i = tid; i < 2 * EPB * 24; i += PBLK) ((float*)h2b)[i] = 0.f;
    if (tid < EPB * FF) {
        int e2 = tid >> 6, f2 = tid & 63;
        xs[0][e2][f2] = x[((long)(b0 + e2) * TT + 0) * FF + f2];
    }
    __syncthreads();

    float c1 = 0.f, c2 = 0.f;
    for (int t = 0; t < TT; ++t) {
        const int cur = t & 1;
        float xpre = 0.f;
        if (t + 1 < TT && tid < EPB * FF) {
            int e2 = tid >> 6, f2 = tid & 63;
            xpre = x[((long)(b0 + e2) * TT + (t + 1)) * FF + f2];
        }
        float zz0 = 0.f, zz1 = 0.f, zz2 = 0.f, zz3 = 0.f;
        const float4* xv = (const float4*)xs[cur][elem];
#pragma unroll
        for (int q = 0; q < FF / 4; ++q) {
            float4 xx = xv[q];
            zz0 = fmaf(xx.x, w1[4*q+0], zz0);
            zz1 = fmaf(xx.y, w1[4*q+1], zz1);
            zz2 = fmaf(xx.z, w1[4*q+2], zz2);
            zz3 = fmaf(xx.w, w1[4*q+3], zz3);
        }
        const float4* hv = (const float4*)h1b[cur][elem];
#pragma unroll
        for (int q = 0; q < HH / 4; ++q) {
            float4 hh = hv[q];
            zz0 = fmaf(hh.x, u1[4*q+0], zz0);
            zz1 = fmaf(hh.y, u1[4*q+1], zz1);
            zz2 = fmaf(hh.z, u1[4*q+2], zz2);
            zz3 = fmaf(hh.w, u1[4*q+3], zz3);
        }
        float z = bias1 + ((zz0 + zz1) + (zz2 + zz3));
        float a = (g == 2) ? fmaxf(z, 0.f) : sigmoidf_(z);
        float a1 = qpx1(a), a2 = qpx2(a), a3 = qpx3(a);
        c1 = a1 * c1 + a * a2;
        float h1n = a3 * fmaxf(c1, 0.f);
        if (g == 0) h1b[cur ^ 1][elem][u] = h1n;
        __syncthreads();
        if (t + 1 < TT && tid < EPB * FF) xs[cur ^ 1][tid >> 6][tid & 63] = xpre;

        float y0 = 0.f, y1 = 0.f, y2 = 0.f, y3 = 0.f;
        const float4* h1v = (const float4*)h1b[cur ^ 1][elem];
        const float4* h2v = (const float4*)h2b[cur][elem];
#pragma unroll
        for (int q = 0; q < HH / 4; ++q) {
            float4 ha = h1v[q];
            float4 hb = h2v[q];
            y0 = fmaf(ha.x, w2[4*q+0], y0);
            y1 = fmaf(ha.y, w2[4*q+1], y1);
            y2 = fmaf(ha.z, w2[4*q+2], y2);
            y3 = fmaf(ha.w, w2[4*q+3], y3);
            y0 = fmaf(hb.x, u2[4*q+0], y0);
            y1 = fmaf(hb.y, u2[4*q+1], y1);
            y2 = fmaf(hb.z, u2[4*q+2], y2);
            y3 = fmaf(hb.w, u2[4*q+3], y3);
        }
        float z2v = bias2 + ((y0 + y1) + (y2 + y3));
        float bgt = (g == 2) ? fmaxf(z2v, 0.f) : sigmoidf_(z2v);
        float b1_ = qpx1(bgt), b2_ = qpx2(bgt), b3_ = qpx3(bgt);
        c2 = b1_ * c2 + bgt * b2_;
        float h2n = b3_ * fmaxf(c2, 0.f);
        if (g == 0) h2b[cur ^ 1][elem][u] = h2n;
        __syncthreads();
    }
    if (j == 0) {
        float acc = bd[0];
#pragma unroll
        for (int k = 0; k < HH; ++k) acc += h2b[0][elem][k] * Wd[k];
        out[b0 + elem] = acc;
    }
}

extern "C" void kernel_launch(void* const* d_in, const int* in_sizes, int n_in,
                              void* d_out, int out_size, void* d_ws, size_t ws_size,
                              hipStream_t stream) {
    const float* x  = (const float*)d_in[0];
    const float* W1 = (const float*)d_in[1];
    const float* U1 = (const float*)d_in[2];
    const float* b1 = (const float*)d_in[3];
    const float* W2 = (const float*)d_in[4];
    const float* U2 = (const float*)d_in[5];
    const float* b2 = (const float*)d_in[6];
    const float* Wd = (const float*)d_in[7];
    const float* bd = (const float*)d_in[8];
    float* out = (float*)d_out;
    const int B = in_sizes[0] / (TT * FF);   // 2048

    const size_t need = (size_t)XW_OFF + (size_t)B * TT * G4 * sizeof(float);
    if (ws_size >= need) {
        float4* blob = (float4*)d_ws;
        unsigned short* wthi = (unsigned short*)((char*)d_ws + WTHI_OFF);
        unsigned short* wtlo = (unsigned short*)((char*)d_ws + WTLO_OFF);
        float* xw = (float*)((char*)d_ws + XW_OFF);
        hipLaunchKernelGGL(wprep, dim3(26), dim3(256), 0, stream,
                           U1, W2, U2, W1, blob, wthi, wtlo);
        hipLaunchKernelGGL(proj_mfma, dim3(B * 2), dim3(256), 0, stream,
                           x, wthi, wtlo, b1, xw, B);
        hipLaunchKernelGGL(lstm2_pc, dim3(B / EPB), dim3(RBLK), 0, stream,
                           xw, blob, b2, Wd, bd, out, B);
    } else {
        hipLaunchKernelGGL(lstm2_fused_fb, dim3(B / EPB), dim3(PBLK), 0, stream,
                           x, W1, U1, b1, W2, U2, b2, Wd, bd, out);
    }
}